// Round 5
// baseline (461.077 us; speedup 1.0000x reference)
//
#include <hip/hip_runtime.h>

// RoiAlign (TF crop_and_resize, bilinear, extrapolation_value=0)
// boxes: [B, N, 4] f32 pixel coords (x1, y1, x2, y2)
// fpn:   [B, H, W, C] f32 (NHWC, C innermost)
// out:   [B, N, 14, 14, C] f32
//
// Journal (dur = 284 us harness overhead + kernels):
// R1/R2: nt output stores.                               gather ~150 us
// R3 (FAILED): fused prefetch blocks — raced, cross-L2.  174 us
// R4 (FAILED): serialized warm pass — L3 hits don't beat HBM. +82 us
// R5 (FAILED): global atomics, 1568-way contention = 800 us/kernel.
// R6 (WASH): (image,row)-sorted + XCD-partitioned gather: ~135 us (-10%).
//   Audit: write scatter is 14 KB-granular (fine); writes can't thrash L2
//   (fill period 21 us >> 2 us reuse window); window 1.8 MB < 4 MB L2.
//   Surviving theory: compulsory 268 MB still demand-missed as x-scattered
//   2 KB chunks -> ~3 TB/s HBM efficiency. (Also retro-explains R4.)
// R7: aligned warm-ahead INSIDE the gather. Sort emits per-(image,row) bin
//   offsets; each wave of bin (b,y0) prefetches chunk q of row y0+2
//   (sequential 1-4 KB pieces, collectively covering each row once) into
//   the SAME XCD L2 that consumes it 2 bins later. Mistimed prefetch
//   degrades to a same-L2 duplicate hit — R3's cross-cache double-pay is
//   structurally excluded. Gather numerics identical to R2.
constexpr int CROP_H = 14;
constexpr int CROP_W = 14;
constexpr int B = 4, N = 256, H = 256, W = 256, C = 256;
constexpr int C4 = C / 4;                          // float4 per pixel
constexpr int POSITIONS = B * N * CROP_H * CROP_W; // 200704
constexpr int ITEMS_PER_IMG = N * CROP_H;          // 3584 box-rows per image
constexpr int ITEMS = B * ITEMS_PER_IMG;           // 14336
constexpr int ROW_F4 = W * C4;                     // 16384 float4 per row (256 KB)
constexpr int NXCD = 8;
constexpr int POS_PER_XCD = POSITIONS / NXCD;      // 25088
// ws layout (u32): offs[1025] | perm[ITEMS] at WS_PERM
constexpr int WS_PERM = 1056;
constexpr size_t WS_NEEDED_BYTES = (size_t)(WS_PERM + ITEMS) * 4;

typedef float vfloat4 __attribute__((ext_vector_type(4)));

// ---- Launch 1: per-image counting sort of box-rows by source row y0. ----
// 4 blocks (one per image) x 256 threads (one per box). LDS-only contention.
// Also emits offs[(b<<8)|y] = global item index of bin start (gather uses
// these to self-assign warm-ahead chunks).
__global__ __launch_bounds__(256) void sort_rows_kernel(
    const float* __restrict__ boxes, unsigned int* __restrict__ ws) {
  __shared__ unsigned int cnt[256];
  __shared__ unsigned int wsum[4];
  const int b = blockIdx.x;           // image
  const int tid = threadIdx.x;        // box within image
  cnt[tid] = 0u;
  __syncthreads();

  // EXACT reference fp sequence for the y path (must match gather's y0).
  const float* bx = boxes + (size_t)(b * N + tid) * 4;
  const float y1 = bx[1], y2 = bx[3];
  const float Hf = (float)H;
  const float ny1 = y1 / Hf * Hf / (Hf - 1.0f);
  const float ny2 = (y2 / Hf * Hf - 1.0f) / (Hf - 1.0f);

  unsigned int mybin[CROP_H];
#pragma unroll
  for (int i = 0; i < CROP_H; ++i) {
    float ty = (float)i / (float)(CROP_H - 1);
    float ys = (ny1 + (ny2 - ny1) * ty) * (Hf - 1.0f);
    float y0f = floorf(ys);
    int y0 = (int)fminf(fmaxf(y0f, 0.0f), Hf - 1.0f);
    mybin[i] = (unsigned)y0;
    atomicAdd(&cnt[y0], 1u);          // LDS atomic
  }
  __syncthreads();

  // Exclusive scan of cnt[256]: per-wave shfl scan + 4-wave fixup.
  unsigned c0 = cnt[tid];
  unsigned v = c0;
#pragma unroll
  for (int d = 1; d < 64; d <<= 1) {
    unsigned u = __shfl_up(v, d);
    if ((tid & 63) >= d) v += u;
  }
  if ((tid & 63) == 63) wsum[tid >> 6] = v;
  __syncthreads();
  if (tid == 0) {
    unsigned acc = 0;
    for (int w = 0; w < 4; ++w) { unsigned t = wsum[w]; wsum[w] = acc; acc += t; }
  }
  __syncthreads();
  const unsigned start = v - c0 + wsum[tid >> 6];     // exclusive scan
  ws[(b << 8) | tid] = (unsigned)(b * ITEMS_PER_IMG) + start;  // bin start (global items)
  if (b == 3 && tid == 0) ws[1024] = (unsigned)ITEMS;          // sentinel
  cnt[tid] = start;
  __syncthreads();

  // Scatter item ids grouped by bin (intra-bin order arbitrary: permutation).
#pragma unroll
  for (int i = 0; i < CROP_H; ++i) {
    unsigned slot = atomicAdd(&cnt[mybin[i]], 1u);    // LDS atomic
    ws[WS_PERM + b * ITEMS_PER_IMG + slot] =
        (unsigned)((b * N + tid) * CROP_H + i);       // global item id
  }
}

// ---- Launch 2: gather in sorted XCD-partitioned order + warm-ahead. ----
template <bool USE_PERM>
__global__ __launch_bounds__(256) void roi_align_kernel(
    const float* __restrict__ boxes,
    const float* __restrict__ fpn,
    float* __restrict__ out,
    const unsigned int* __restrict__ ws) {
  const int wave = threadIdx.x >> 6;
  const int lane = threadIdx.x & 63;

  int pos;
  int slot = 0;
  if (USE_PERM) {
    // XCD x (blockIdx % 8, HW round-robin) owns sorted slots
    // [x*25088, (x+1)*25088): contiguous row sweep per XCD.
    const int xcd = blockIdx.x & 7;
    const int r   = blockIdx.x >> 3;
    slot = xcd * POS_PER_XCD + r * 4 + wave;
    const unsigned it = (unsigned)slot / 14u;       // sorted item index
    const unsigned jj = (unsigned)slot - it * 14u;  // j within the box-row
    pos = (int)(ws[WS_PERM + it] * 14u + jj);
  } else {
    pos = blockIdx.x * 4 + wave;
  }

  int j = pos % CROP_W;
  int t = pos / CROP_W;
  int i = t % CROP_H;
  t /= CROP_H;
  int n = t % N;
  int b = t / N;

  const float* bx = boxes + (size_t)(b * N + n) * 4;
  float x1 = bx[0], y1 = bx[1], x2 = bx[2], y2 = bx[3];

  // Replicate the reference's exact fp32 normalization sequence.
  const float Hf = (float)H, Wf = (float)W;
  float ny1 = y1 / Hf * Hf / (Hf - 1.0f);
  float nx1 = x1 / Wf * Wf / (Wf - 1.0f);
  float ny2 = (y2 / Hf * Hf - 1.0f) / (Hf - 1.0f);
  float nx2 = (x2 / Wf * Wf - 1.0f) / (Wf - 1.0f);

  float ty = (float)i / (float)(CROP_H - 1);
  float tx = (float)j / (float)(CROP_W - 1);
  float ys = (ny1 + (ny2 - ny1) * ty) * (Hf - 1.0f);
  float xs = (nx1 + (nx2 - nx1) * tx) * (Wf - 1.0f);

  bool valid = (ys >= 0.0f) && (ys <= Hf - 1.0f) &&
               (xs >= 0.0f) && (xs <= Wf - 1.0f);

  float y0f = floorf(ys), x0f = floorf(xs);
  float wy = ys - y0f, wx = xs - x0f;
  int y0  = (int)fminf(fmaxf(y0f,        0.0f), Hf - 1.0f);
  int y1i = (int)fminf(fmaxf(y0f + 1.0f, 0.0f), Hf - 1.0f);
  int x0  = (int)fminf(fmaxf(x0f,        0.0f), Wf - 1.0f);
  int x1i = (int)fminf(fmaxf(x0f + 1.0f, 0.0f), Wf - 1.0f);

  const float4* f4 = (const float4*)fpn;
  int rb = b * H;

  if (USE_PERM) {
    // ---- Warm-ahead: this wave prefetches chunk q of row (y0+2) into its
    // own XCD's L2. Bin (b,y0) has s_pos waves; wave q streams `share` KB at
    // offset q*share KB; collectively the 256 KB row is covered once,
    // sequentially. Result is sunk; timing slack = 2 row-bins of schedule.
    const unsigned bin = ((unsigned)b << 8) | (unsigned)y0;
    const unsigned o0 = ws[bin];
    const unsigned o1 = ws[bin + 1];
    const int s_pos = (int)(o1 - o0) * 14;          // waves in this bin (>=14)
    const int q = slot - (int)o0 * 14;              // this wave's index in bin
    int share = (256 + s_pos - 1) / s_pos;          // KB per wave
    if (share > 4) share = 4;
    const int rowt = (y0 + 2 <= H - 1) ? (y0 + 2) : (H - 1);
    const float4* rowbase = f4 + (size_t)(rb + rowt) * ROW_F4;
    const int kb0 = q * share;
    float acc = 0.0f;
    if (kb0 < 256) {
      for (int l = 0; l < share; ++l) {
        if (kb0 + l < 256) {                        // stay inside the row
          float4 v = rowbase[(size_t)(kb0 + l) * 64 + lane];
          acc += v.x;
        }
      }
    }
    asm volatile("" :: "v"(acc));                   // sink: keep loads alive
  }

  size_t i00 = (size_t)((rb + y0)  * W + x0)  * C4 + lane;
  size_t i01 = (size_t)((rb + y0)  * W + x1i) * C4 + lane;
  size_t i10 = (size_t)((rb + y1i) * W + x0)  * C4 + lane;
  size_t i11 = (size_t)((rb + y1i) * W + x1i) * C4 + lane;

  float4 tl = f4[i00];
  float4 tr = f4[i01];
  float4 bl = f4[i10];
  float4 br = f4[i11];

  float w00 = (1.0f - wy) * (1.0f - wx);
  float w01 = (1.0f - wy) * wx;
  float w10 = wy * (1.0f - wx);
  float w11 = wy * wx;

  vfloat4 o;
  o.x = tl.x * w00 + tr.x * w01 + bl.x * w10 + br.x * w11;
  o.y = tl.y * w00 + tr.y * w01 + bl.y * w10 + br.y * w11;
  o.z = tl.z * w00 + tr.z * w01 + bl.z * w10 + br.z * w11;
  o.w = tl.w * w00 + tr.w * w01 + bl.w * w10 + br.w * w11;
  if (!valid) { o.x = 0.0f; o.y = 0.0f; o.z = 0.0f; o.w = 0.0f; }

  // nt store: the 205 MB output stream has no reuse — keep it out of L2/L3.
  vfloat4* dst = (vfloat4*)out + (size_t)pos * C4 + lane;
  __builtin_nontemporal_store(o, dst);
}

extern "C" void kernel_launch(void* const* d_in, const int* in_sizes, int n_in,
                              void* d_out, int out_size, void* d_ws, size_t ws_size,
                              hipStream_t stream) {
  const float* boxes = (const float*)d_in[0];  // [B, N, 4]
  const float* fpn   = (const float*)d_in[1];  // [B, H, W, C]
  float* out = (float*)d_out;                  // [B, N, 14, 14, C]

  if (d_ws != nullptr && ws_size >= WS_NEEDED_BYTES) {
    unsigned int* ws = (unsigned int*)d_ws;
    hipLaunchKernelGGL(sort_rows_kernel, dim3(B), dim3(256), 0, stream,
                       boxes, ws);
    hipLaunchKernelGGL(roi_align_kernel<true>, dim3(POSITIONS / 4), dim3(256),
                       0, stream, boxes, fpn, out, ws);
  } else {
    // Workspace too small: fall back to the verified R2 schedule.
    hipLaunchKernelGGL(roi_align_kernel<false>, dim3(POSITIONS / 4), dim3(256),
                       0, stream, boxes, fpn, out, (const unsigned int*)nullptr);
  }
}